// Round 1
// baseline (403.611 us; speedup 1.0000x reference)
//
#include <hip/hip_runtime.h>
#include <math.h>

#define HH 512
#define WW 512
#define BB 32
#define KK 8
#define SPLIT 8
#define CHUNK ((HH * WW) / SPLIT)   // 32768 floats per block
#define BLOCK 256

// Kernel 1: partial argmax per (b,k) segment.
// grid = B*K*SPLIT blocks; block `blk` handles segment (blk % SPLIT) of pair (blk / SPLIT).
__global__ __launch_bounds__(BLOCK) void argmax_partial(
    const float* __restrict__ hm, float* __restrict__ pval, int* __restrict__ pidx)
{
    const int blk = blockIdx.x;
    const int seg = blk % SPLIT;
    const int bk  = blk / SPLIT;
    const int t   = threadIdx.x;

    const float4* base =
        reinterpret_cast<const float4*>(hm + (size_t)bk * (HH * WW) + (size_t)seg * CHUNK);

    float bv = -INFINITY;
    int   bi = 0x7fffffff;

    const int n4 = CHUNK / 4;  // 8192 float4 per block
    // per-thread index sequence is strictly increasing, so strict '>' keeps the
    // first occurrence (matches jnp.argmax tie semantics within a thread)
    for (int i = t; i < n4; i += BLOCK) {
        float4 v = base[i];
        int i0 = seg * CHUNK + i * 4;
        if (v.x > bv) { bv = v.x; bi = i0;     }
        if (v.y > bv) { bv = v.y; bi = i0 + 1; }
        if (v.z > bv) { bv = v.z; bi = i0 + 2; }
        if (v.w > bv) { bv = v.w; bi = i0 + 3; }
    }

    __shared__ float sv[BLOCK];
    __shared__ int   si[BLOCK];
    sv[t] = bv; si[t] = bi;
    __syncthreads();
    for (int s = BLOCK / 2; s > 0; s >>= 1) {
        if (t < s) {
            float ov = sv[t + s]; int oi = si[t + s];
            // tie-break: lower flat index wins (first occurrence)
            if (ov > sv[t] || (ov == sv[t] && oi < si[t])) { sv[t] = ov; si[t] = oi; }
        }
        __syncthreads();
    }
    if (t == 0) { pval[blk] = sv[0]; pidx[blk] = si[0]; }
}

// Kernel 2: one block, 256 threads; thread t = (b,k) pair.
__global__ __launch_bounds__(BLOCK) void finalize(
    const float* __restrict__ pval, const int* __restrict__ pidx,
    const float* __restrict__ gt,
    const float* __restrict__ m0, const float* __restrict__ m1,
    const float* __restrict__ m2, float* __restrict__ out)
{
    const int t = threadIdx.x;        // t in [0, 256) = b*K + k
    const int b = t / KK;

    // reduce SPLIT partials; segments are in increasing-index order, so
    // strict '>' with low-index tie-break reproduces first-max semantics
    float bv = -INFINITY;
    int   bi = 0x7fffffff;
    for (int s = 0; s < SPLIT; ++s) {
        float v = pval[t * SPLIT + s];
        int   i = pidx[t * SPLIT + s];
        if (v > bv || (v == bv && i < bi)) { bv = v; bi = i; }
    }

    const float x = (float)(bi % WW) * (1.0f / (WW - 1));
    const float y = (float)(bi / WW) * (1.0f / (HH - 1));

    // reference: kx = clip(x, 0, 511); ix = floor(kx)  (x in [0,1] -> ix in {0,1})
    const float kx = fminf(fmaxf(x, 0.0f), 511.0f);
    const float ky = fminf(fmaxf(y, 0.0f), 511.0f);
    const int ix = (int)floorf(kx);
    const int iy = (int)floorf(ky);
    const float fx = fabsf(x - (float)ix);
    const float fy = fabsf(y - (float)iy);

    // reference gathers padding_mask[b, ix, iy]: x-coord indexes dim-1 (rows)
    const size_t mo = (size_t)b * (HH * WW) + (size_t)ix * WW + (size_t)iy;
    const float g0 = m0[mo];
    const float g1 = m1[mo];
    const float g2 = m2[mo];

    const float gtx = gt[t * 2 + 0];
    const float gty = gt[t * 2 + 1];

    // per-(b,k) contribution:
    //   |x-gtx| + |y-gty|                       (loss_kpts_sum)
    // + 3 * 10 * (fx + fy)                      (quant_off in each of 3 offsets, *10)
    // + 10 * 10 * ((1-g0) + (1-g1) + (1-g2))    (mask_off * PADDING_LOSS_VALUE * 10)
    float loss = fabsf(x - gtx) + fabsf(y - gty)
               + 30.0f  * (fx + fy)
               + 100.0f * (3.0f - g0 - g1 - g2);

    __shared__ float ss[BLOCK];
    ss[t] = loss;
    __syncthreads();
    for (int s = BLOCK / 2; s > 0; s >>= 1) {
        if (t < s) ss[t] += ss[t + s];
        __syncthreads();
    }
    if (t == 0) out[0] = ss[0];
}

extern "C" void kernel_launch(void* const* d_in, const int* in_sizes, int n_in,
                              void* d_out, int out_size, void* d_ws, size_t ws_size,
                              hipStream_t stream)
{
    const float* hm = (const float*)d_in[0];   // (32, 8, 512, 512) f32
    const float* gt = (const float*)d_in[1];   // (32, 8, 2) f32
    const float* m0 = (const float*)d_in[2];   // (32, 512, 512) f32
    const float* m1 = (const float*)d_in[3];
    const float* m2 = (const float*)d_in[4];

    float* pval = (float*)d_ws;                              // 2048 floats
    int*   pidx = (int*)((char*)d_ws + BB * KK * SPLIT * sizeof(float)); // 2048 ints

    argmax_partial<<<BB * KK * SPLIT, BLOCK, 0, stream>>>(hm, pval, pidx);
    finalize<<<1, BLOCK, 0, stream>>>(pval, pidx, gt, m0, m1, m2, (float*)d_out);
}